// Round 12
// baseline (1190.539 us; speedup 1.0000x reference)
//
#include <hip/hip_runtime.h>
#include <math.h>

// Model dims: H=512 D=128 L=8 T=64 W=240 CTX=60 NSTEPS=30

typedef __attribute__((ext_vector_type(8))) short short8;
typedef __attribute__((ext_vector_type(4))) float floatx4;
typedef unsigned long long ull;

__device__ __forceinline__ float sigf(float x) { return 1.f / (1.f + __expf(-x)); }
__device__ __forceinline__ float tanh_f(float x) {
    float e = __expf(2.f * x);
    return 1.f - 2.f / (e + 1.f);
}
__device__ __forceinline__ unsigned short f2b(float x) {   // fp32 -> bf16 RNE
    unsigned u = __float_as_uint(x);
    unsigned r = (u + 0x7FFFu + ((u >> 16) & 1u)) >> 16;
    return (unsigned short)r;
}

// RELAXED agent-scope atomics only (acquire/release emit buffer_inv/wbl2 on
// gfx950 and trash the XCD L2). Cross-block payloads are {epoch|data} ull
// words polled directly (data+readiness in one MALL round trip), batch-polled.
// R16: init_k is REMOVED. Every epoch-0 slot is published by its owner with
// the normal protocol (zero word = {epoch 0 | h=0}): enc blocks zero-publish
// their 512 exchange words at startup (hidden under the weight load), pyr
// blocks their 16, precomp blocks 0/1 cover hdec slots 0/1. Safety: consumers'
// exact-epoch polls at the FIRST use of each slot gate on these writes; a
// zero word (epoch 0) never matches later polls; stale words from prior graph
// replays are epoch-checked at the first poll of each slot before any later
// poll reads them (per-word overwrites are monotone within a run).
__device__ __forceinline__ float gld(const float* p) {
    return __hip_atomic_load(p, __ATOMIC_RELAXED, __HIP_MEMORY_SCOPE_AGENT);
}
__device__ __forceinline__ void gst(float* p, float v) {
    __hip_atomic_store(p, v, __ATOMIC_RELAXED, __HIP_MEMORY_SCOPE_AGENT);
}
__device__ __forceinline__ ull gldll(const ull* p) {
    return __hip_atomic_load(p, __ATOMIC_RELAXED, __HIP_MEMORY_SCOPE_AGENT);
}
__device__ __forceinline__ void gstll(ull* p, ull v) {
    __hip_atomic_store(p, v, __ATOMIC_RELAXED, __HIP_MEMORY_SCOPE_AGENT);
}
__device__ __forceinline__ ull packfe(float d, int ep) {
    return ((ull)(unsigned)ep << 32) | (ull)__float_as_uint(d);
}
__device__ __forceinline__ float lowf(ull v) { return __uint_as_float((unsigned)v); }

// ---------------------------------------------------------------------------
// Encoder R16: 240 blocks x 512 thr; group fg=bid>>3 (8 frames), slice
// ds=bid&7 (64 h-dims). Exchange buffer [2][30][2048] {epoch|bf16x2}.
// Startup: each block zero-publishes its 512 words (both slots) BEFORE the
// weight load so consumers' t=0/t=1 polls are fed while weights stream.
// ---------------------------------------------------------------------------
__global__ void __launch_bounds__(512, 1) enc_all(
    const float* __restrict__ data,
    const float* __restrict__ Wih, const float* __restrict__ Whh,
    const float* __restrict__ bih, const float* __restrict__ bhh,
    ull* __restrict__ hbufF,        // [2][30][2048] {epoch|bf16x2}
    float* __restrict__ henc)       // [240][512] fp32 final h
{
    __shared__ short act2[20 * 64 * 8];   // 16 h-tiles + 4 x-tiles; rows f>=8 zero
    __shared__ float gw[8][32 * 21];      // per wave: 32 gate-rows x 21 (16f+pad5)
    __shared__ float biasL[256];

    const int tid = threadIdx.x;
    const int fg = blockIdx.x >> 3, ds = blockIdx.x & 7;
    const int w = tid >> 6, lane = tid & 63;
    const int n = lane & 15, q = lane >> 4;
    const int ef = tid >> 6, edp = tid & 63;   // elementwise: frame, dim

    // ---- startup: zero-publish own exchange words (both slots) ----
    {
        int slot = tid >> 8, i = tid & 255;
        int f = i & 7, dpair = i >> 3;          // 0..31
        int d = ds * 64 + 2 * dpair;
        int widx = (d >> 5) * 128 + f * 16 + ((d >> 3) & 3) * 4 + ((d >> 1) & 3);
        gstll(hbufF + (size_t)(slot * 30 + fg) * 2048 + widx, 0ULL);
    }

    // weights: wave w covers block-rows rr = w*32 + nt*16 + n (256 rows total)
    short8 bfrag[2][20];
#pragma unroll
    for (int nt = 0; nt < 2; ++nt) {
        int rr = w * 32 + nt * 16 + n;
        int g = rr >> 6, dp = rr & 63;
        int grow = g * 512 + ds * 64 + dp;
#pragma unroll
        for (int kt = 0; kt < 20; ++kt) {
            int k0 = kt * 32 + q * 8;
            const float* src = (k0 < 512) ? (Whh + (size_t)grow * 512 + k0)
                                          : (Wih + (size_t)grow * 128 + (k0 - 512));
            float4 lo = *(const float4*)src;
            float4 hi = *(const float4*)(src + 4);
            short8 bf;
            bf[0] = (short)f2b(lo.x); bf[1] = (short)f2b(lo.y);
            bf[2] = (short)f2b(lo.z); bf[3] = (short)f2b(lo.w);
            bf[4] = (short)f2b(hi.x); bf[5] = (short)f2b(hi.y);
            bf[6] = (short)f2b(hi.z); bf[7] = (short)f2b(hi.w);
            bfrag[nt][kt] = bf;
        }
    }
    if (tid < 256) {
        int g = tid >> 6, dp = tid & 63;
        int grow = g * 512 + ds * 64 + dp;
        biasL[tid] = bih[grow] + bhh[grow];
    }
    unsigned* a2u = (unsigned*)act2;
    for (int i = tid; i < 5120; i += 512) a2u[i] = 0;   // one-time: rows f>=8 stay 0
    __syncthreads();

    float creg = 0.f;    // c-state for (ef, edp) lives in a register

    for (int t = 0; t < 64; ++t) {
        // x prefetch FIRST (no h dep): frame ef, dim pair kx
        const int kx = 2 * edp;                    // 0..126
        const float* xs = data + ((size_t)t * 240 + fg * 8 + ef) * 128 + kx;
        float2 xv = *(const float2*)xs;

        // h gather: batch-poll 4 {epoch|bf16x2} words (ONE MALL window)
        {
            const ull* hsrc = hbufF + (size_t)((t & 1) * 30 + fg) * 2048;
            ull v[4];
            for (;;) {
                bool ok = true;
#pragma unroll
                for (int k2 = 0; k2 < 4; ++k2) {
                    v[k2] = gldll(hsrc + tid + 512 * k2);
                    ok &= ((int)(v[k2] >> 32) == t);
                }
                if (ok) break;
                __builtin_amdgcn_s_sleep(1);
            }
#pragma unroll
            for (int k2 = 0; k2 < 4; ++k2) {
                int widx = tid + 512 * k2;
                int kt = widx >> 7, r = widx & 127;
                int f = r >> 4, qq = (r >> 2) & 3, e2 = r & 3;
                a2u[(kt * 64 + f + 16 * qq) * 4 + e2] = (unsigned)v[k2];
            }
        }
        {   // x into act2 (tiles 16..19), 2 bf16 per thread
            int kt2 = 16 + (kx >> 5), qq = (kx >> 3) & 3;
            unsigned px = (unsigned)f2b(xv.x) | ((unsigned)f2b(xv.y) << 16);
            a2u[(kt2 * 64 + ef + 16 * qq) * 4 + ((kx & 7) >> 1)] = px;
        }
        __syncthreads();

        floatx4 acc0 = {0.f, 0.f, 0.f, 0.f};
        floatx4 acc1 = {0.f, 0.f, 0.f, 0.f};
#pragma unroll
        for (int kt = 0; kt < 20; ++kt) {
            short8 a = *(short8*)&act2[(kt * 64 + lane) * 8];
            acc0 = __builtin_amdgcn_mfma_f32_16x16x32_bf16(a, bfrag[0][kt], acc0, 0, 0, 0);
            acc1 = __builtin_amdgcn_mfma_f32_16x16x32_bf16(a, bfrag[1][kt], acc1, 0, 0, 0);
        }
        *(floatx4*)&gw[w][(0 * 16 + n) * 21 + 4 * q] = acc0;
        *(floatx4*)&gw[w][(1 * 16 + n) * 21 + 4 * q] = acc1;
        __syncthreads();

        // elementwise: thread (ef, edp); gate g at block-row rr = g*64 + edp
        float g0, g1, g2v, g3;
        {
            int rr0 = 0 * 64 + edp, rr1 = 1 * 64 + edp, rr2 = 2 * 64 + edp, rr3 = 3 * 64 + edp;
            g0 = gw[rr0 >> 5][(rr0 & 31) * 21 + ef] + biasL[rr0];
            g1 = gw[rr1 >> 5][(rr1 & 31) * 21 + ef] + biasL[rr1];
            g2v = gw[rr2 >> 5][(rr2 & 31) * 21 + ef] + biasL[rr2];
            g3 = gw[rr3 >> 5][(rr3 & 31) * 21 + ef] + biasL[rr3];
        }
        float cn = sigf(g1) * creg + sigf(g0) * tanh_f(g2v);
        float hn = sigf(g3) * tanh_f(cn);
        creg = cn;
        if (t == 63)
            gst(&henc[(size_t)(fg * 8 + ef) * 512 + ds * 64 + edp], hn);

        // publish: even-dim lanes pack (hn, partner) into one word
        float hnn = __shfl_xor(hn, 1);
        if ((edp & 1) == 0) {
            int d = ds * 64 + edp;
            unsigned pv = (unsigned)f2b(hn) | ((unsigned)f2b(hnn) << 16);
            int widx = (d >> 5) * 128 + ef * 16 + ((d >> 3) & 3) * 4 + ((d >> 1) & 3);
            gstll(hbufF + (size_t)(((t + 1) & 1) * 30 + fg) * 2048 + widx,
                  ((ull)(unsigned)(t + 1) << 32) | (ull)pv);
        }
        __syncthreads();
    }
}

// ---------------------------------------------------------------------------
// xp GEMM stage 1 (A = henc), F/B pair fused (unchanged).
// ---------------------------------------------------------------------------
__global__ void __launch_bounds__(256) gemm_xp2(
    const float* __restrict__ A, int M, int K, int halfgrid,
    const float* __restrict__ WvF, const float* __restrict__ baF,
    const float* __restrict__ bbF, float* __restrict__ CF,
    const float* __restrict__ WvB, const float* __restrict__ baB,
    const float* __restrict__ bbB, float* __restrict__ CB)
{
    __shared__ float At[16][66];
    __shared__ float Wt[128][66];
    const int tid = threadIdx.x;
    int bgl = blockIdx.x;
    const int rev = (bgl >= halfgrid) ? 1 : 0;
    if (rev) bgl -= halfgrid;
    const float* Wv = rev ? WvB : WvF;
    const float* ba = rev ? baB : baF;
    const float* bb = rev ? bbB : bbF;
    float* C        = rev ? CB : CF;

    const int nt = bgl & 15, mt = bgl >> 4;
    const int rp = tid >> 2, fq = tid & 3;
    const int lr0 = 2 * rp, lr1 = lr0 + 1;
    const int n0 = nt * 128 + lr0, n1 = n0 + 1;

    float acc0[4], acc1[4];
    {
        float b0 = ba[n0] + bb[n0], b1 = ba[n1] + bb[n1];
#pragma unroll
        for (int j = 0; j < 4; ++j) { acc0[j] = b0; acc1[j] = b1; }
    }

    for (int kt = 0; kt < K; kt += 64) {
        {
            int f = tid >> 4, c4 = tid & 15;
            int m = mt * 16 + f;
            float4 v = make_float4(0.f, 0.f, 0.f, 0.f);
            if (m < M) {
                int ar = rev ? (M - 1 - m) : m;
                v = ((const float4*)(A + (size_t)ar * K + kt))[c4];
            }
            At[f][c4 * 4 + 0] = v.x; At[f][c4 * 4 + 1] = v.y;
            At[f][c4 * 4 + 2] = v.z; At[f][c4 * 4 + 3] = v.w;
        }
        for (int i = tid; i < 2048; i += 256) {
            int lr = i >> 4, c4 = i & 15;
            float4 v = ((const float4*)(Wv + (size_t)(nt * 128 + lr) * K + kt))[c4];
            Wt[lr][c4 * 4 + 0] = v.x; Wt[lr][c4 * 4 + 1] = v.y;
            Wt[lr][c4 * 4 + 2] = v.z; Wt[lr][c4 * 4 + 3] = v.w;
        }
        __syncthreads();
        const float2* w0p = (const float2*)(&Wt[lr0][0]);
        const float2* w1p = (const float2*)(&Wt[lr1][0]);
#pragma unroll 8
        for (int kh = 0; kh < 32; ++kh) {
            float2 w0 = w0p[kh], w1 = w1p[kh];
#pragma unroll
            for (int j = 0; j < 4; ++j) {
                float2 av = ((const float2*)(&At[4 * fq + j][0]))[kh];
                acc0[j] += w0.x * av.x + w0.y * av.y;
                acc1[j] += w1.x * av.x + w1.y * av.y;
            }
        }
        __syncthreads();
    }
#pragma unroll
    for (int j = 0; j < 4; ++j) {
        int m = mt * 16 + 4 * fq + j;
        if (m < M) {
            C[(size_t)m * 2048 + n0] = acc0[j];
            C[(size_t)m * 2048 + n1] = acc1[j];
        }
    }
}

// ---------------------------------------------------------------------------
// xp GEMM stage 2 reading the virtual x2 directly from f1/b1o (unchanged).
// ---------------------------------------------------------------------------
__global__ void __launch_bounds__(256) gemm_x2(
    const float* __restrict__ f1, const float* __restrict__ b1o,
    int M, int K, int halfgrid,
    const float* __restrict__ WvF, const float* __restrict__ baF,
    const float* __restrict__ bbF, float* __restrict__ CF,
    const float* __restrict__ WvB, const float* __restrict__ baB,
    const float* __restrict__ bbB, float* __restrict__ CB)
{
    __shared__ float At[16][66];
    __shared__ float Wt[128][66];
    const int tid = threadIdx.x;
    int bgl = blockIdx.x;
    const int rev = (bgl >= halfgrid) ? 1 : 0;
    if (rev) bgl -= halfgrid;
    const float* Wv = rev ? WvB : WvF;
    const float* ba = rev ? baB : baF;
    const float* bb = rev ? bbB : bbF;
    float* C        = rev ? CB : CF;

    const int nt = bgl & 15, mt = bgl >> 4;
    const int rp = tid >> 2, fq = tid & 3;
    const int lr0 = 2 * rp, lr1 = lr0 + 1;
    const int n0 = nt * 128 + lr0, n1 = n0 + 1;

    float acc0[4], acc1[4];
    {
        float b0 = ba[n0] + bb[n0], b1 = ba[n1] + bb[n1];
#pragma unroll
        for (int j = 0; j < 4; ++j) { acc0[j] = b0; acc1[j] = b1; }
    }

    for (int kt = 0; kt < K; kt += 64) {
        {
            int f = tid >> 4, c4 = tid & 15;
            int m = mt * 16 + f;
            float4 v = make_float4(0.f, 0.f, 0.f, 0.f);
            if (m < M) {
                int ar = rev ? (M - 1 - m) : m;
                int seg = kt >> 9;              // 0..3 (K=2048)
                int r = (kt & 511) + 4 * c4;    // within 512-block
                const float* src = (seg & 1) ? b1o : f1;
                int srow = 2 * ar + (seg >> 1);
                v = *(const float4*)&src[(size_t)srow * 512 + r];
            }
            At[f][c4 * 4 + 0] = v.x; At[f][c4 * 4 + 1] = v.y;
            At[f][c4 * 4 + 2] = v.z; At[f][c4 * 4 + 3] = v.w;
        }
        for (int i = tid; i < 2048; i += 256) {
            int lr = i >> 4, c4 = i & 15;
            float4 v = ((const float4*)(Wv + (size_t)(nt * 128 + lr) * K + kt))[c4];
            Wt[lr][c4 * 4 + 0] = v.x; Wt[lr][c4 * 4 + 1] = v.y;
            Wt[lr][c4 * 4 + 2] = v.z; Wt[lr][c4 * 4 + 3] = v.w;
        }
        __syncthreads();
        const float2* w0p = (const float2*)(&Wt[lr0][0]);
        const float2* w1p = (const float2*)(&Wt[lr1][0]);
#pragma unroll 8
        for (int kh = 0; kh < 32; ++kh) {
            float2 w0 = w0p[kh], w1 = w1p[kh];
#pragma unroll
            for (int j = 0; j < 4; ++j) {
                float2 av = ((const float2*)(&At[4 * fq + j][0]))[kh];
                acc0[j] += w0.x * av.x + w0.y * av.y;
                acc1[j] += w1.x * av.x + w1.y * av.y;
            }
        }
        __syncthreads();
    }
#pragma unroll
    for (int j = 0; j < 4; ++j) {
        int m = mt * 16 + 4 * fq + j;
        if (m < M) {
            C[(size_t)m * 2048 + n0] = acc0[j];
            C[(size_t)m * 2048 + n1] = acc1[j];
        }
    }
}

// ---------------------------------------------------------------------------
// Pyramidal bi-LSTM (R14 structure). R16: self-publishes its 16 epoch-0
// words at startup (replaces init_k zeroing).
// ---------------------------------------------------------------------------
__global__ void __launch_bounds__(256, 1) pyr_rec(
    const float* __restrict__ xpF, const float* __restrict__ xpB,
    const float* __restrict__ WhhF, const float* __restrict__ WhhB,
    ull* __restrict__ hp,      // [dir][2][512]
    float* __restrict__ outF, float* __restrict__ outB,
    int steps)
{
    const int tid = threadIdx.x;
    const int dir = blockIdx.x >> 6, blk = blockIdx.x & 63;
    const float* xp  = dir ? xpB : xpF;
    const float* Whh = dir ? WhhB : WhhF;
    float* outp = dir ? outB : outF;
    ull* hpd = hp + (size_t)dir * 1024;

    __shared__ __align__(16) float hcur[512];
    __shared__ float gv[32];

    // startup: zero-publish own words in both slots
    if (tid < 16) {
        int slot = tid >> 3, j = tid & 7;
        gstll(&hpd[(size_t)slot * 512 + blk * 8 + j], 0ULL);
    }

    const int row = tid >> 3, seg = tid & 7;   // 32 rows x 8 segs
    const int grow = (row >> 3) * 512 + blk * 8 + (row & 7);
    float4 wl4[16];
#pragma unroll
    for (int j = 0; j < 16; ++j)
        wl4[j] = *(const float4*)&Whh[(size_t)grow * 512 + 4 * seg + 32 * j];

    float creg = 0.f;
    __syncthreads();

    for (int t = 0; t < steps; ++t) {
        float xg = 0.f;
        if (seg == 0) xg = xp[(size_t)t * 2048 + grow];   // prefetch (no h dep)
        {
            const ull* base = hpd + (size_t)(t & 1) * 512;
            ull v0 = gldll(base + tid), v1 = gldll(base + tid + 256);
            while (((int)(v0 >> 32) != t) | ((int)(v1 >> 32) != t)) {
                __builtin_amdgcn_s_sleep(1);
                v0 = gldll(base + tid);
                v1 = gldll(base + tid + 256);
            }
            hcur[tid]       = lowf(v0);
            hcur[tid + 256] = lowf(v1);
        }
        __syncthreads();

        float a = 0.f;
#pragma unroll
        for (int j = 0; j < 16; ++j) {
            float4 w = wl4[j];
            float4 h4 = *(const float4*)&hcur[4 * seg + 32 * j];
            a += w.x*h4.x + w.y*h4.y + w.z*h4.z + w.w*h4.w;
        }
        a += __shfl_xor(a, 1);
        a += __shfl_xor(a, 2);
        a += __shfl_xor(a, 4);
        if (seg == 0) gv[row] = a + xg;
        __syncthreads();

        if (tid < 8) {
            float i_ = sigf(gv[tid]), f_ = sigf(gv[8 + tid]);
            float g_ = tanh_f(gv[16 + tid]), o_ = sigf(gv[24 + tid]);
            creg = f_ * creg + i_ * g_;
            float hn = o_ * tanh_f(creg);
            int d = blk * 8 + tid;
            gstll(&hpd[((t + 1) & 1) * 512 + d], packfe(hn, t + 1));
            int row2 = dir ? (steps - 1 - t) : t;
            outp[(size_t)row2 * 512 + d] = hn;
        }
        __syncthreads();
    }
}

// ---------------------------------------------------------------------------
// precompute M^T directly from f2/b2o; block 0 publishes hdec slot0 epoch-0,
// block 1 zeroes hdec slot1 (epoch 0 never matches odd polls).
// ---------------------------------------------------------------------------
__global__ void __launch_bounds__(256) precomp_M(
    const float* __restrict__ comb_W,   // [512][1032]
    const float* __restrict__ f2,       // [60][512]
    const float* __restrict__ b2o,      // [60][512]
    float* __restrict__ MgT,            // [60][512]
    ull* __restrict__ hdec_p)           // [2][512]
{
    __shared__ float cw[8 * 1024];      // 32 KB: comb_W rows d0..d0+8, cols 8..1032
    const int tid = threadIdx.x, d0 = blockIdx.x * 8;
    for (int i = tid; i < 2048; i += 256) {
        int r = i >> 8, c4 = i & 255;
        float4 v = *(const float4*)&comb_W[(size_t)(d0 + r) * 1032 + 8 + 4 * c4];
        *(float4*)&cw[r * 1024 + 4 * c4] = v;
    }
    if (blockIdx.x == 0) {
        for (int i = tid; i < 512; i += 256)
            hdec_p[i] = packfe(f2[59 * 512 + i], 0);
    } else if (blockIdx.x == 1) {
        for (int i = tid; i < 512; i += 256)
            gstll(&hdec_p[512 + i], 0ULL);
    }
    __syncthreads();
    for (int o = tid; o < 480; o += 256) {
        int dl = o / 60, j = o % 60;
        const float4* cp0 = (const float4*)&cw[dl * 1024];          // k 0..511
        const float4* cp1 = (const float4*)&cw[dl * 1024 + 512];    // k 512..1023
        const float4* xf = (const float4*)(f2 + (size_t)j * 512);
        const float4* xb = (const float4*)(b2o + (size_t)j * 512);
        float a = 0.f;
#pragma unroll 4
        for (int k = 0; k < 128; ++k) {
            float4 w = cp0[k], x = xf[k];
            a += w.x * x.x + w.y * x.y + w.z * x.z + w.w * x.w;
        }
#pragma unroll 4
        for (int k = 0; k < 128; ++k) {
            float4 w = cp1[k], x = xb[k];
            a += w.x * x.x + w.y * x.y + w.z * x.z + w.w * x.w;
        }
        MgT[(size_t)j * 512 + (d0 + dl)] = a;
    }
}

// ---------------------------------------------------------------------------
// Decoder (unchanged from R11): 64 blocks x 512 threads, register weights,
// shuffle reductions, conflict-free LDS mappings, 1-word/thread h poll.
// ---------------------------------------------------------------------------
__global__ void __launch_bounds__(512, 1) dec_k(
    const float* __restrict__ attn_W, const float* __restrict__ attn_b,
    const float* __restrict__ comb_W, const float* __restrict__ comb_b,
    const float* __restrict__ gWih, const float* __restrict__ gWhh,
    const float* __restrict__ gbih, const float* __restrict__ gbhh,
    const float* __restrict__ outW, const float* __restrict__ outb,
    const float* __restrict__ MgT,  // [60][512]
    ull* __restrict__ hdec_p,       // [2][512]
    float* __restrict__ dout)
{
    const int tid = threadIdx.x, bid = blockIdx.x;   // 64 blocks x 512 thr
    const int lane = tid & 63, wv = tid >> 6;
    const int dbase = bid * 8;

    __shared__ float M2T[68][512];                   // rows: [M(60) | Minp(8)]
    __shared__ __align__(16) float hL[520];          // h(512) + pad
    __shared__ __align__(16) float xl[512];          // o
    __shared__ __align__(16) float awx[68];          // [aw(60); inp(8)]
    __shared__ float zd[8], zh[64];
    __shared__ float ghl[24], gil[24];
    __shared__ float biasg[24], biasi[24];
    __shared__ float cbL[512];
    __shared__ float attnbL[64], outbL[8];

    // row/seg partitions
    const int rg = tid >> 4, sg = tid & 15;   // gh/gi: 24(32) rows x 16 segs
    const int rz = tid >> 3, szz = tid & 7;   // z_h: 60(64) rows x 8 segs

    // ---- weights to registers (interleaved k-mappings) ----
    float4 wo2[2];                  // logits row wv: k = 4*lane + 256*i
    float4 wg8[8], wi8[8];          // gh/gi row rg:  k = 4*sg + 64*i
    float4 wzh[16];                 // z_h row rz:    k = 4*szz + 32*i
    float4 wip[2];                  // z inp-part (row tid<60)
    {
        const float* wp = outW + (size_t)wv * 512 + 4 * lane;
        wo2[0] = *(const float4*)wp;
        wo2[1] = *(const float4*)(wp + 256);
    }
    {
        int rr = (rg < 24) ? rg : 23;
        size_t grow = (size_t)((rr >> 3) * 512 + dbase + (rr & 7)) * 512 + 4 * sg;
#pragma unroll
        for (int i = 0; i < 8; ++i) {
            wg8[i] = *(const float4*)&gWhh[grow + 64 * i];
            wi8[i] = *(const float4*)&gWih[grow + 64 * i];
        }
    }
    {
        int rr = (rz < 60) ? rz : 59;
        size_t base = (size_t)rr * 520 + 8 + 4 * szz;
#pragma unroll
        for (int i = 0; i < 16; ++i)
            wzh[i] = *(const float4*)&attn_W[base + 32 * i];
    }
    {
        int rr = (tid < 60) ? tid : 59;
        wip[0] = *(const float4*)&attn_W[(size_t)rr * 520 + 0];
        wip[1] = *(const float4*)&attn_W[(size_t)rr * 520 + 4];
    }
    if (tid < 24) {
        int g2 = (tid >> 3) * 512 + dbase + (tid & 7);
        biasg[tid] = gbhh[g2];
        biasi[tid] = gbih[g2];
    }
    cbL[tid] = comb_b[tid];
    if (tid < 64) attnbL[tid] = (tid < 60) ? attn_b[tid] : 0.f;
    if (tid < 8) outbL[tid] = outb[tid];
    // M2T rows 0..59 from MgT (coalesced), rows 60..67 = comb_W cols 0..8
    for (int i = tid; i < 7680; i += 512) {
        int j = i >> 7, c4 = i & 127;
        *(float4*)&M2T[j][4 * c4] = *(const float4*)&MgT[(size_t)j * 512 + 4 * c4];
    }
    for (int i = tid; i < 4096; i += 512) {
        int r = i >> 3, c = i & 7;
        M2T[60 + c][r] = comb_W[(size_t)r * 1032 + c];
    }
    __syncthreads();

    for (int s = 0; s < 30; ++s) {
        // ---- cross-block hop: h (slot s&1, epoch s), 1 word/thread ----
        {
            const ull* hs = hdec_p + (size_t)(s & 1) * 512;
            ull v0 = gldll(hs + tid);
            while ((int)(v0 >> 32) != s) {
                __builtin_amdgcn_s_sleep(1);
                v0 = gldll(hs + tid);
            }
            hL[tid] = lowf(v0);
        }
        __syncthreads();

        // ---- phase A: three h-matvec partials + shuffle reductions ----
        {   // logits: one wave per row, contiguous 16B-stride reads
            float a = 0.f;
            float4 h0 = *(const float4*)&hL[4 * lane];
            float4 h1 = *(const float4*)&hL[4 * lane + 256];
            a += wo2[0].x*h0.x + wo2[0].y*h0.y + wo2[0].z*h0.z + wo2[0].w*h0.w;
            a += wo2[1].x*h1.x + wo2[1].y*h1.y + wo2[1].z*h1.z + wo2[1].w*h1.w;
#pragma unroll
            for (int off = 32; off; off >>= 1) a += __shfl_xor(a, off);
            if (lane == 0) zd[wv] = a;
        }
        {   // gh: 16 segs, k = 4*sg + 64*i
            float a = 0.f;
#pragma unroll
            for (int i = 0; i < 8; ++i) {
                float4 w = wg8[i];
                float4 h4 = *(const float4*)&hL[4 * sg + 64 * i];
                a += w.x*h4.x + w.y*h4.y + w.z*h4.z + w.w*h4.w;
            }
            a += __shfl_xor(a, 1); a += __shfl_xor(a, 2);
            a += __shfl_xor(a, 4); a += __shfl_xor(a, 8);
            if (sg == 0 && rg < 24) ghl[rg] = a;
        }
        {   // z_h: 8 segs, k = 4*szz + 32*i
            float a = 0.f;
#pragma unroll
            for (int i = 0; i < 16; ++i) {
                float4 w = wzh[i];
                float4 h4 = *(const float4*)&hL[4 * szz + 32 * i];
                a += w.x*h4.x + w.y*h4.y + w.z*h4.z + w.w*h4.w;
            }
            a += __shfl_xor(a, 1); a += __shfl_xor(a, 2); a += __shfl_xor(a, 4);
            if (szz == 0 && rz < 60) zh[rz] = a;
        }
        __syncthreads();

        // ---- phase BC (wave 0): inp -> z finalize -> softmax60 ----
        if (wv == 0) {
            if (lane < 8) {
                float v;
                if (s > 0) {
                    float a = zd[lane] + outbL[lane];
                    float m = a;
                    m = fmaxf(m, __shfl_xor(m, 1));
                    m = fmaxf(m, __shfl_xor(m, 2));
                    m = fmaxf(m, __shfl_xor(m, 4));
                    float e = __expf(a - m);
                    float ss2 = e;
                    ss2 += __shfl_xor(ss2, 1);
                    ss2 += __shfl_xor(ss2, 2);
                    ss2 += __shfl_xor(ss2, 4);
                    v = a - m - __logf(ss2);
                    if (bid == 0) dout[(s - 1) * 8 + lane] = v;
                } else {
                    v = (lane == 7) ? 1.f : 0.f;
                }
                awx[60 + lane] = v;
            }
            // z = zh + b + attn_W[:,0:8] @ inp  (same-wave LDS ordering)
            float z = -1e30f;
            if (lane < 60) {
                z = zh[lane] + attnbL[lane]
                  + wip[0].x * awx[60] + wip[0].y * awx[61]
                  + wip[0].z * awx[62] + wip[0].w * awx[63]
                  + wip[1].x * awx[64] + wip[1].y * awx[65]
                  + wip[1].z * awx[66] + wip[1].w * awx[67];
            }
            float m = z;
#pragma unroll
            for (int off = 32; off; off >>= 1) m = fmaxf(m, __shfl_xor(m, off));
            float e = (lane < 60) ? __expf(z - m) : 0.f;
            float ss2 = e;
#pragma unroll
            for (int off = 32; off; off >>= 1) ss2 += __shfl_xor(ss2, off);
            if (lane < 60) awx[lane] = e / ss2;
        }
        __syncthreads();

        // ---- phase E: o = relu(M2T^T @ [aw; inp] + comb_b), 1 dim/thread ----
        {
            float a = cbL[tid];
#pragma unroll 4
            for (int k = 0; k < 68; ++k)
                a += M2T[k][tid] * awx[k];
            xl[tid] = fmaxf(a, 0.f);
        }
        __syncthreads();

        // ---- phase F: gi = gWih @ o, k = 4*sg + 64*i ----
        {
            float a = 0.f;
#pragma unroll
            for (int i = 0; i < 8; ++i) {
                float4 w = wi8[i];
                float4 o4 = *(const float4*)&xl[4 * sg + 64 * i];
                a += w.x*o4.x + w.y*o4.y + w.z*o4.z + w.w*o4.w;
            }
            a += __shfl_xor(a, 1); a += __shfl_xor(a, 2);
            a += __shfl_xor(a, 4); a += __shfl_xor(a, 8);
            if (sg == 0 && rg < 24) gil[rg] = a;
        }
        __syncthreads();

        // ---- phase G: GRU combine + publish (8 threads) ----
        if (tid < 8) {
            float gh0 = biasg[tid] + ghl[tid];
            float gh1 = biasg[8 + tid] + ghl[8 + tid];
            float gh2 = biasg[16 + tid] + ghl[16 + tid];
            float gi0 = biasi[tid] + gil[tid];
            float gi1 = biasi[8 + tid] + gil[8 + tid];
            float gi2 = biasi[16 + tid] + gil[16 + tid];
            float r_ = sigf(gi0 + gh0);
            float z_ = sigf(gi1 + gh1);
            float n_ = tanh_f(gi2 + r_ * gh2);
            float hnew = (1.f - z_) * n_ + z_ * hL[dbase + tid];
            gstll(&hdec_p[(size_t)((s + 1) & 1) * 512 + dbase + tid], packfe(hnew, s + 1));
        }
        __syncthreads();   // protect hL/awx/xl before next-step overwrite
    }

    // epilogue: logits for s=29 (block 0 only)
    if (bid == 0) {
        {
            const ull* hs = hdec_p + (size_t)(30 & 1) * 512;
            ull v0 = gldll(hs + tid);
            while ((int)(v0 >> 32) != 30) {
                __builtin_amdgcn_s_sleep(1);
                v0 = gldll(hs + tid);
            }
            hL[tid] = lowf(v0);
        }
        __syncthreads();
        {
            float a = 0.f;
            float4 h0 = *(const float4*)&hL[4 * lane];
            float4 h1 = *(const float4*)&hL[4 * lane + 256];
            a += wo2[0].x*h0.x + wo2[0].y*h0.y + wo2[0].z*h0.z + wo2[0].w*h0.w;
            a += wo2[1].x*h1.x + wo2[1].y*h1.y + wo2[1].z*h1.z + wo2[1].w*h1.w;
#pragma unroll
            for (int off = 32; off; off >>= 1) a += __shfl_xor(a, off);
            if (lane == 0) zd[wv] = a;
        }
        __syncthreads();
        if (tid < 8) {
            float a = zd[tid] + outbL[tid];
            float m = a;
            m = fmaxf(m, __shfl_xor(m, 1));
            m = fmaxf(m, __shfl_xor(m, 2));
            m = fmaxf(m, __shfl_xor(m, 4));
            float e = __expf(a - m);
            float ss2 = e;
            ss2 += __shfl_xor(ss2, 1);
            ss2 += __shfl_xor(ss2, 2);
            ss2 += __shfl_xor(ss2, 4);
            dout[29 * 8 + tid] = a - m - __logf(ss2);
        }
    }
}

// ---------------------------------------------------------------------------
extern "C" void kernel_launch(void* const* d_in, const int* in_sizes, int n_in,
                              void* d_out, int out_size, void* d_ws, size_t ws_size,
                              hipStream_t stream) {
    (void)in_sizes; (void)n_in; (void)out_size; (void)ws_size;
    const float* data    = (const float*)d_in[0];
    const float* enc_Wih = (const float*)d_in[1];
    const float* enc_Whh = (const float*)d_in[2];
    const float* enc_bih = (const float*)d_in[3];
    const float* enc_bhh = (const float*)d_in[4];
    const float* p1f_Wih = (const float*)d_in[5];
    const float* p1f_Whh = (const float*)d_in[6];
    const float* p1f_bih = (const float*)d_in[7];
    const float* p1f_bhh = (const float*)d_in[8];
    const float* p1b_Wih = (const float*)d_in[9];
    const float* p1b_Whh = (const float*)d_in[10];
    const float* p1b_bih = (const float*)d_in[11];
    const float* p1b_bhh = (const float*)d_in[12];
    const float* p2f_Wih = (const float*)d_in[13];
    const float* p2f_Whh = (const float*)d_in[14];
    const float* p2f_bih = (const float*)d_in[15];
    const float* p2f_bhh = (const float*)d_in[16];
    const float* p2b_Wih = (const float*)d_in[17];
    const float* p2b_Whh = (const float*)d_in[18];
    const float* p2b_bih = (const float*)d_in[19];
    const float* p2b_bhh = (const float*)d_in[20];
    const float* attn_W  = (const float*)d_in[21];
    const float* attn_b  = (const float*)d_in[22];
    const float* comb_W  = (const float*)d_in[23];
    const float* comb_b  = (const float*)d_in[24];
    const float* gru_Wih = (const float*)d_in[25];
    const float* gru_Whh = (const float*)d_in[26];
    const float* gru_bih = (const float*)d_in[27];
    const float* gru_bhh = (const float*)d_in[28];
    const float* out_W   = (const float*)d_in[29];
    const float* out_b   = (const float*)d_in[30];

    float* ws = (float*)d_ws;
    // exchange buffers (self-initialized via epoch-0 publishes; no init kernel)
    ull* hbufF   = (ull*)ws;                 // 245760 floats = [2][30][2048] ull
    ull* hp1     = (ull*)(ws + 245760);      // 4096 floats = [2][2][512] ull
    ull* hp2     = (ull*)(ws + 249856);      // 4096 floats
    ull* hdec_p  = (ull*)(ws + 253952);      // 2048 floats -> end 256000
    // scratch
    float* henc  = ws + 256000;              // 122880
    float* xp1f  = ws + 378880;              // 245760
    float* xp1b  = ws + 624640;              // 245760
    float* f1    = ws + 870400;              // 61440
    float* b1o   = ws + 931840;              // 61440
    float* xp2f  = ws + 993280;              // 122880
    float* xp2b  = ws + 1116160;             // 122880
    float* f2    = ws + 1239040;             // 30720
    float* b2o   = ws + 1269760;             // 30720
    float* MgT   = ws + 1300480;             // 30720 -> end 1331200

    enc_all<<<240, 512, 0, stream>>>(data, enc_Wih, enc_Whh, enc_bih, enc_bhh,
                                     hbufF, henc);
    gemm_xp2<<<256, 256, 0, stream>>>(henc, 120, 1024, 128,
                                      p1f_Wih, p1f_bih, p1f_bhh, xp1f,
                                      p1b_Wih, p1b_bih, p1b_bhh, xp1b);
    pyr_rec<<<128, 256, 0, stream>>>(xp1f, xp1b, p1f_Whh, p1b_Whh, hp1, f1, b1o, 120);
    gemm_x2<<<128, 256, 0, stream>>>(f1, b1o, 60, 2048, 64,
                                     p2f_Wih, p2f_bih, p2f_bhh, xp2f,
                                     p2b_Wih, p2b_bih, p2b_bhh, xp2b);
    pyr_rec<<<128, 256, 0, stream>>>(xp2f, xp2b, p2f_Whh, p2b_Whh, hp2, f2, b2o, 60);
    precomp_M<<<64, 256, 0, stream>>>(comb_W, f2, b2o, MgT, hdec_p);
    dec_k<<<64, 512, 0, stream>>>(attn_W, attn_b, comb_W, comb_b,
                                  gru_Wih, gru_Whh, gru_bih, gru_bhh,
                                  out_W, out_b, MgT, hdec_p,
                                  (float*)d_out);
}